// Round 9
// baseline (723.987 us; speedup 1.0000x reference)
//
#include <hip/hip_runtime.h>

#define D 128
#define NG 256

typedef __attribute__((ext_vector_type(8))) short bf16x8;
typedef __attribute__((ext_vector_type(4))) float f32x4;
typedef __attribute__((ext_vector_type(4))) float f4;
typedef __attribute__((ext_vector_type(4))) ushort u16x4;

__device__ inline ushort f2bf(float f) {
  uint b = __float_as_uint(f);
  return (ushort)((b + 0x7fffu + ((b >> 16) & 1u)) >> 16);
}
__device__ inline float bf2f(ushort u) { return __uint_as_float((uint)u << 16); }

// ------- fused: per-chunk deg histograms + per-graph counts + x->bf16 + W->bf16^T -------
// deg is [2N]: [0,N) = chunk0 (e < E0), [N,2N) = chunk1 (e >= E0)
__global__ __launch_bounds__(256) void prep_kernel(
    const int* __restrict__ ei, int* __restrict__ deg,
    const int* __restrict__ batch, const int* __restrict__ primary,
    int* __restrict__ ncount, int* __restrict__ ccnt,
    const float* __restrict__ x, ushort* __restrict__ xb,
    const float* __restrict__ W1, const float* __restrict__ W2,
    ushort* __restrict__ W1T, ushort* __restrict__ W2T, int E, int E0, int N, int total4) {
  int i = blockIdx.x * blockDim.x + threadIdx.x;
  if (i < E) {
    int d = ei[E + i];
    atomicAdd(&deg[(i >= E0 ? N : 0) + d], 1);
  }
  if (i < N) {
    int g = batch[i];
    atomicAdd(&ncount[g], 1);
    if (primary[i] == 0) atomicAdd(&ccnt[g], 1);
  }
  if (i < total4) {
    f4 v = __builtin_nontemporal_load(&((const f4*)x)[i]);
    u16x4 o;
    o.x = f2bf(v.x); o.y = f2bf(v.y); o.z = f2bf(v.z); o.w = f2bf(v.w);
    ((u16x4*)xb)[i] = o;
  }
  if (i < 2 * D * D) {
    int w = i >> 14;
    int k = (i >> 7) & 127;
    int n = i & 127;
    const float* src = w ? W2 : W1;
    ushort* dst = w ? W2T : W1T;
    dst[n * 128 + k] = f2bf(src[k * 128 + n]);
  }
}

// ---------------- scan over N2 elements (3-phase) ----------------
__global__ __launch_bounds__(256) void scan_block_sums(const int* __restrict__ deg,
                                                       int* __restrict__ bsum, int N2) {
  __shared__ int red[256];
  int t = threadIdx.x;
  int base = blockIdx.x * 1024;
  int s = 0;
#pragma unroll
  for (int j = 0; j < 4; ++j) {
    int i = base + t * 4 + j;
    if (i < N2) s += deg[i];
  }
  red[t] = s;
  __syncthreads();
  for (int o = 128; o > 0; o >>= 1) {
    if (t < o) red[t] += red[t + o];
    __syncthreads();
  }
  if (t == 0) bsum[blockIdx.x] = red[0];
}

// parallel exclusive scan of nb (<=256) block sums
__global__ void scan_bsum(int* __restrict__ bsum, int nb) {
  __shared__ int a[256];
  int t = threadIdx.x;
  int v = (t < nb) ? bsum[t] : 0;
  a[t] = v;
  __syncthreads();
  for (int o = 1; o < 256; o <<= 1) {
    int u = (t >= o) ? a[t - o] : 0;
    __syncthreads();
    a[t] += u;
    __syncthreads();
  }
  if (t < nb) bsum[t] = a[t] - v;
}

__global__ __launch_bounds__(256) void scan_final(const int* __restrict__ deg,
                                                  const int* __restrict__ bsum,
                                                  int* __restrict__ off, int N2) {
  __shared__ int ts[256];
  int t = threadIdx.x;
  int base = blockIdx.x * 1024;
  int v[4];
  int s = 0;
#pragma unroll
  for (int j = 0; j < 4; ++j) {
    int i = base + t * 4 + j;
    v[j] = (i < N2) ? deg[i] : 0;
    s += v[j];
  }
  ts[t] = s;
  __syncthreads();
  for (int o = 1; o < 256; o <<= 1) {
    int u = (t >= o) ? ts[t - o] : 0;
    __syncthreads();
    ts[t] += u;
    __syncthreads();
  }
  int excl = ts[t] - s + bsum[blockIdx.x];
#pragma unroll
  for (int j = 0; j < 4; ++j) {
    int i = base + t * 4 + j;
    if (i < N2) off[i] = excl;
    excl += v[j];
    if (i == N2 - 1) off[N2] = excl;
  }
}

// ---------------- msg build (chunk): sequential ea read, L3-cached random row write -------
// 32 lanes per edge. msg[offc[d]-rowbase+slot] = bf16(ea[e] + x_bf[src])  (PLAIN stores)
__global__ __launch_bounds__(256, 8) void msg_build_kernel(
    const int* __restrict__ ei, const ushort* __restrict__ xb,
    const float* __restrict__ ea, const int* __restrict__ offc,
    int* __restrict__ cursorc, ushort* __restrict__ msg,
    int ebase, int ecnt, int E, int rowbase) {
  long long t = (long long)blockIdx.x * 256 + threadIdx.x;
  int rel = (int)(t >> 5);
  int c = (int)(t & 31);
  if (rel >= ecnt) return;
  int e = ebase + rel;
  int s = ei[e];
  int d = ei[E + e];
  int slot;
  if (c == 0) slot = atomicAdd(&cursorc[d], 1);
  slot = __shfl(slot, 0, 32);
  long long row = (long long)offc[d] - rowbase + slot;
  f4 a = __builtin_nontemporal_load(&((const f4*)ea)[(size_t)e * 32 + c]);
  u16x4 u = ((const u16x4*)xb)[(size_t)s * 32 + c];
  u16x4 o;
  o.x = f2bf(a.x + bf2f(u.x));
  o.y = f2bf(a.y + bf2f(u.y));
  o.z = f2bf(a.z + bf2f(u.z));
  o.w = f2bf(a.w + bf2f(u.w));
  ((u16x4*)msg)[(size_t)row * 32 + c] = o;  // plain store: let L3 retain it
}

// ---------------- reduce chunk0: agg[n] = x_bf[n] + sum(msg rows) (f32) ----------------
__global__ __launch_bounds__(256, 8) void reduce0_kernel(
    const ushort* __restrict__ xb, const ushort* __restrict__ msg,
    const int* __restrict__ off0, float* __restrict__ agg, int N) {
  long long t = (long long)blockIdx.x * 256 + threadIdx.x;
  int n = (int)(t >> 5);
  int c = (int)(t & 31);
  if (n >= N) return;
  const u16x4* msg4 = (const u16x4*)msg;
  u16x4 self = ((const u16x4*)xb)[(size_t)n * 32 + c];
  f4 acc;
  acc.x = bf2f(self.x); acc.y = bf2f(self.y); acc.z = bf2f(self.z); acc.w = bf2f(self.w);
  int k = off0[n];
  const int e = off0[n + 1];
  for (; k + 4 <= e; k += 4) {
    u16x4 u0 = msg4[(size_t)k * 32 + c];
    u16x4 u1 = msg4[(size_t)(k + 1) * 32 + c];
    u16x4 u2 = msg4[(size_t)(k + 2) * 32 + c];
    u16x4 u3 = msg4[(size_t)(k + 3) * 32 + c];
    acc.x += bf2f(u0.x) + bf2f(u1.x);
    acc.y += bf2f(u0.y) + bf2f(u1.y);
    acc.z += bf2f(u0.z) + bf2f(u1.z);
    acc.w += bf2f(u0.w) + bf2f(u1.w);
    acc.x += bf2f(u2.x) + bf2f(u3.x);
    acc.y += bf2f(u2.y) + bf2f(u3.y);
    acc.z += bf2f(u2.z) + bf2f(u3.z);
    acc.w += bf2f(u2.w) + bf2f(u3.w);
  }
  for (; k < e; ++k) {
    u16x4 u0 = msg4[(size_t)k * 32 + c];
    acc.x += bf2f(u0.x);
    acc.y += bf2f(u0.y);
    acc.z += bf2f(u0.z);
    acc.w += bf2f(u0.w);
  }
  ((f4*)agg)[(size_t)n * 32 + c] = acc;
}

// ---------------- reduce chunk1: yb[n] = bf16(agg[n] + sum(msg rows)) ----------------
__global__ __launch_bounds__(256, 8) void reduce1_kernel(
    const float* __restrict__ agg, const ushort* __restrict__ msg,
    const int* __restrict__ off1, int rowbase, ushort* __restrict__ yb, int N) {
  long long t = (long long)blockIdx.x * 256 + threadIdx.x;
  int n = (int)(t >> 5);
  int c = (int)(t & 31);
  if (n >= N) return;
  const u16x4* msg4 = (const u16x4*)msg;
  f4 acc = ((const f4*)agg)[(size_t)n * 32 + c];
  int k = off1[n] - rowbase;
  const int e = off1[n + 1] - rowbase;
  for (; k + 4 <= e; k += 4) {
    u16x4 u0 = msg4[(size_t)k * 32 + c];
    u16x4 u1 = msg4[(size_t)(k + 1) * 32 + c];
    u16x4 u2 = msg4[(size_t)(k + 2) * 32 + c];
    u16x4 u3 = msg4[(size_t)(k + 3) * 32 + c];
    acc.x += bf2f(u0.x) + bf2f(u1.x);
    acc.y += bf2f(u0.y) + bf2f(u1.y);
    acc.z += bf2f(u0.z) + bf2f(u1.z);
    acc.w += bf2f(u0.w) + bf2f(u1.w);
    acc.x += bf2f(u2.x) + bf2f(u3.x);
    acc.y += bf2f(u2.y) + bf2f(u3.y);
    acc.z += bf2f(u2.z) + bf2f(u3.z);
    acc.w += bf2f(u2.w) + bf2f(u3.w);
  }
  for (; k < e; ++k) {
    u16x4 u0 = msg4[(size_t)k * 32 + c];
    acc.x += bf2f(u0.x);
    acc.y += bf2f(u0.y);
    acc.z += bf2f(u0.z);
    acc.w += bf2f(u0.w);
  }
  u16x4 o;
  o.x = f2bf(acc.x); o.y = f2bf(acc.y); o.z = f2bf(acc.z); o.w = f2bf(acc.w);
  ((u16x4*)yb)[(size_t)n * 32 + c] = o;
}

// ---------------- exclusive scan of graph sizes -> gstart ----------------
__global__ void scan_kernel(const int* __restrict__ ncount, int* __restrict__ gstart) {
  __shared__ int a[NG];
  int tx = threadIdx.x;
  int v = ncount[tx];
  a[tx] = v;
  __syncthreads();
  for (int off = 1; off < NG; off <<= 1) {
    int u = (tx >= off) ? a[tx - off] : 0;
    __syncthreads();
    a[tx] += u;
    __syncthreads();
  }
  gstart[tx] = a[tx] - v;
  if (tx == NG - 1) gstart[NG] = a[tx];
}

// ---------------- per-graph stable ranks: primary -> p, cond -> ~p ----------------
__global__ __launch_bounds__(256) void rank_kernel(const int* __restrict__ primary,
                                                   const int* __restrict__ gstart,
                                                   const int* __restrict__ ccnt,
                                                   int* __restrict__ pos) {
  int g = blockIdx.x;
  int s = gstart[g], e = gstart[g + 1];
  int pcnt = (e - s) - ccnt[g];
  __shared__ int wcntP[4], wcntC[4];
  int prun = 0, crun = 0;
  for (int i0 = s; i0 < e; i0 += 256) {
    int n = i0 + threadIdx.x;
    bool valid = n < e;
    int isP = (valid && primary[n] == 1) ? 1 : 0;
    int isC = (valid && primary[n] != 1) ? 1 : 0;
    unsigned long long mP = __ballot(isP);
    unsigned long long mC = __ballot(isC);
    int lane = threadIdx.x & 63;
    int wid = threadIdx.x >> 6;
    if (lane == 0) { wcntP[wid] = __popcll(mP); wcntC[wid] = __popcll(mC); }
    __syncthreads();
    int preP = __popcll(mP & ((1ULL << lane) - 1ULL));
    int preC = __popcll(mC & ((1ULL << lane) - 1ULL));
    int woffP = 0, woffC = 0;
#pragma unroll
    for (int ww = 0; ww < 4; ++ww)
      if (ww < wid) { woffP += wcntP[ww]; woffC += wcntC[ww]; }
    int totP = wcntP[0] + wcntP[1] + wcntP[2] + wcntP[3];
    int totC = wcntC[0] + wcntC[1] + wcntC[2] + wcntC[3];
    if (valid) {
      if (isP)
        pos[n] = s + prun + woffP + preP;
      else
        pos[n] = ~(s + pcnt + crun + woffC + preC);
    }
    prun += totP;
    crun += totC;
    __syncthreads();
  }
}

// ---------------- MFMA MLP: writes out rows directly + fused cond-pool sum ----------------
__global__ __launch_bounds__(256) void mlp_mfma_kernel(
    const ushort* __restrict__ yb, float* __restrict__ out,
    const ushort* __restrict__ W1T, const float* __restrict__ b1,
    const ushort* __restrict__ W2T, const float* __restrict__ b2,
    const int* __restrict__ batch, const int* __restrict__ primary,
    const int* __restrict__ pos, float* __restrict__ csum, int N) {
  __shared__ ushort tl[4][16][D];  // per-wave relu(t) tile, XOR-swizzled cols
  __shared__ float csl[4][D];      // local csum for up to 4 graphs
  const int tid = threadIdx.x;
  const int w = tid >> 6;
  const int l = tid & 63;
  const int lr = l & 15;
  const int lg = l >> 4;
  const int base = blockIdx.x * 64;
  const int m0 = base + w * 16;

  for (int i = tid; i < 4 * D; i += 256) ((float*)csl)[i] = 0.f;
  int gmin = batch[base < N ? base : N - 1];
  __syncthreads();

  // GEMM1: t = relu(y @ W1 + b1)
  f32x4 acc[8];
#pragma unroll
  for (int t = 0; t < 8; ++t) {
    float bv = b1[t * 16 + lr];
    acc[t][0] = bv; acc[t][1] = bv; acc[t][2] = bv; acc[t][3] = bv;
  }
  int arow = m0 + lr;
  if (arow >= N) arow = N - 1;
#pragma unroll
  for (int kk = 0; kk < 4; ++kk) {
    bf16x8 a = *(const bf16x8*)&yb[(size_t)arow * D + kk * 32 + lg * 8];
#pragma unroll
    for (int t = 0; t < 8; ++t) {
      bf16x8 b = *(const bf16x8*)&W1T[(size_t)(t * 16 + lr) * D + kk * 32 + lg * 8];
      acc[t] = __builtin_amdgcn_mfma_f32_16x16x32_bf16(a, b, acc[t], 0, 0, 0);
    }
  }
  // relu + cvt + store to per-wave LDS tile ([m][n], col ^= (m&7)<<3)
#pragma unroll
  for (int t = 0; t < 8; ++t) {
#pragma unroll
    for (int r = 0; r < 4; ++r) {
      float v = acc[t][r];
      v = v > 0.f ? v : 0.f;
      int m = lg * 4 + r;
      int col = (t * 16 + lr) ^ ((m & 7) << 3);
      tl[w][m][col] = f2bf(v);
    }
  }
  __syncthreads();

  // GEMM2: h = t @ W2 + b2
  f32x4 acc2[8];
#pragma unroll
  for (int t = 0; t < 8; ++t) {
    float bv = b2[t * 16 + lr];
    acc2[t][0] = bv; acc2[t][1] = bv; acc2[t][2] = bv; acc2[t][3] = bv;
  }
#pragma unroll
  for (int kk = 0; kk < 4; ++kk) {
    bf16x8 a = *(const bf16x8*)&tl[w][lr][(kk * 32 + lg * 8) ^ ((lr & 7) << 3)];
#pragma unroll
    for (int t = 0; t < 8; ++t) {
      bf16x8 b = *(const bf16x8*)&W2T[(size_t)(t * 16 + lr) * D + kk * 32 + lg * 8];
      acc2[t] = __builtin_amdgcn_mfma_f32_16x16x32_bf16(a, b, acc2[t], 0, 0, 0);
    }
  }

  // epilogue: direct out-row writes + cond-pool accumulation
#pragma unroll
  for (int r = 0; r < 4; ++r) {
    int m = m0 + lg * 4 + r;
    if (m >= N) continue;
    int p = pos[m];
    if (p >= 0) {  // primary: left half = h
      size_t ro = (size_t)p * 256;
#pragma unroll
      for (int t = 0; t < 8; ++t)
        __builtin_nontemporal_store(acc2[t][r], &out[ro + t * 16 + lr]);
    } else {  // cond: zero full row, accumulate into pool sum
      size_t ro = (size_t)(~p) * 256;
#pragma unroll
      for (int t = 0; t < 8; ++t) {
        __builtin_nontemporal_store(0.0f, &out[ro + t * 16 + lr]);
        __builtin_nontemporal_store(0.0f, &out[ro + 128 + t * 16 + lr]);
      }
      int g = batch[m];
      int gl = g - gmin;
      if (gl < 4) {
#pragma unroll
        for (int t = 0; t < 8; ++t) atomicAdd(&csl[gl][t * 16 + lr], acc2[t][r]);
      } else {
#pragma unroll
        for (int t = 0; t < 8; ++t)
          unsafeAtomicAdd(&csum[(size_t)g * D + t * 16 + lr], acc2[t][r]);
      }
    }
  }
  __syncthreads();
  for (int i = tid; i < 4 * D; i += 256) {
    float v = ((float*)csl)[i];
    if (v != 0.f) {
      int gl = i >> 7, c = i & 127;
      unsafeAtomicAdd(&csum[(size_t)(gmin + gl) * D + c], v);
    }
  }
}

// ---------------- right half of primary rows: out[p][128+c] = csum[g][c]/cnt ----------------
__global__ __launch_bounds__(256) void poolwrite_kernel(const float* __restrict__ csum,
                                                        const int* __restrict__ ccnt,
                                                        const int* __restrict__ batch,
                                                        const int* __restrict__ pos,
                                                        float* __restrict__ out, int N) {
  long long tid = (long long)blockIdx.x * blockDim.x + threadIdx.x;
  int n = (int)(tid >> 5);
  int c = (int)(tid & 31);
  if (n >= N) return;
  int p = pos[n];
  if (p < 0) return;
  int g = batch[n];
  int cnt = ccnt[g];
  f4 v = {0.f, 0.f, 0.f, 0.f};
  if (cnt > 0) {
    f4 s4 = ((const f4*)csum)[(size_t)g * 32 + c];
    float inv = 1.0f / (float)cnt;
    v = s4 * inv;
  }
  __builtin_nontemporal_store(v, &((f4*)out)[(size_t)p * 64 + 32 + c]);
}

extern "C" void kernel_launch(void* const* d_in, const int* in_sizes, int n_in,
                              void* d_out, int out_size, void* d_ws, size_t ws_size,
                              hipStream_t stream) {
  const float* x = (const float*)d_in[0];
  const int* ei = (const int*)d_in[1];
  const float* ea = (const float*)d_in[2];
  const int* batch = (const int*)d_in[3];
  const int* primary = (const int*)d_in[4];
  const float* W1 = (const float*)d_in[5];
  const float* b1 = (const float*)d_in[6];
  const float* W2 = (const float*)d_in[7];
  const float* b2 = (const float*)d_in[8];
  float* out = (float*)d_out;

  const int N = in_sizes[0] / D;   // 100000
  const int E = in_sizes[1] / 2;   // 1600000
  const int E0 = E / 2;            // chunk split
  const int N2 = 2 * N;
  const int nb = (N2 + 1023) / 1024;
  const int total4 = N * D / 4;
  const int Emax = E - E0;         // larger chunk size (E odd-safe)

  // workspace layout
  float* csum = (float*)d_ws;                        // NG*D f32
  float* agg = csum + (size_t)NG * D;                // N*D f32
  ushort* xb = (ushort*)(agg + (size_t)N * D);       // N*D bf16
  ushort* yb = xb + (size_t)N * D;                   // N*D bf16
  ushort* W1T = yb + (size_t)N * D;                  // D*D bf16
  ushort* W2T = W1T + D * D;                         // D*D bf16
  ushort* msg = W2T + D * D;                         // Emax*D bf16 (205 MB, reused per chunk)
  int* ip = (int*)(msg + (size_t)Emax * D);
  int* deg = ip;                                     // 2N
  int* OFF = deg + N2;                               // 2N+1 (pad 4)
  int* cursor = OFF + N2 + 4;                        // 2N  (cursor0 | cursor1)
  int* bsum = cursor + N2;                           // nb (pad 256)
  int* ccnt = bsum + 256;                            // NG
  int* ncount = ccnt + NG;                           // NG
  int* gstart = ncount + NG;                         // NG+1 (pad 260)
  int* pos = gstart + 260;                           // N

  hipMemsetAsync(csum, 0, (size_t)NG * D * 4, stream);
  hipMemsetAsync(deg, 0, (size_t)N2 * 4, stream);
  hipMemsetAsync(cursor, 0, (size_t)N2 * 4, stream);
  hipMemsetAsync(ccnt, 0, (size_t)NG * 2 * 4, stream);  // ccnt + ncount contiguous

  prep_kernel<<<(total4 + 255) / 256, 256, 0, stream>>>(ei, deg, batch, primary, ncount, ccnt,
                                                        x, xb, W1, W2, W1T, W2T, E, E0, N,
                                                        total4);
  scan_block_sums<<<nb, 256, 0, stream>>>(deg, bsum, N2);
  scan_bsum<<<1, 256, 0, stream>>>(bsum, nb);
  scan_final<<<nb, 256, 0, stream>>>(deg, bsum, OFF, N2);
  scan_kernel<<<1, NG, 0, stream>>>(ncount, gstart);
  rank_kernel<<<NG, 256, 0, stream>>>(primary, gstart, ccnt, pos);

  // ---- chunk 0 ----
  {
    long long threads = (long long)E0 * 32;
    msg_build_kernel<<<(int)((threads + 255) / 256), 256, 0, stream>>>(ei, xb, ea, OFF, cursor,
                                                                       msg, 0, E0, E, 0);
  }
  {
    long long threads = (long long)N * 32;
    reduce0_kernel<<<(int)((threads + 255) / 256), 256, 0, stream>>>(xb, msg, OFF, agg, N);
  }
  // ---- chunk 1 ----
  {
    long long threads = (long long)(E - E0) * 32;
    msg_build_kernel<<<(int)((threads + 255) / 256), 256, 0, stream>>>(ei, xb, ea, OFF + N,
                                                                       cursor + N, msg, E0,
                                                                       E - E0, E, E0);
  }
  {
    long long threads = (long long)N * 32;
    reduce1_kernel<<<(int)((threads + 255) / 256), 256, 0, stream>>>(agg, msg, OFF + N, E0, yb,
                                                                     N);
  }

  mlp_mfma_kernel<<<(N + 63) / 64, 256, 0, stream>>>(yb, out, W1T, b1, W2T, b2, batch, primary,
                                                     pos, csum, N);
  poolwrite_kernel<<<(int)(((long long)N * 32 + 255) / 256), 256, 0, stream>>>(csum, ccnt, batch,
                                                                               pos, out, N);
}

// Round 10
// 628.277 us; speedup vs baseline: 1.1523x; 1.1523x over previous
//
#include <hip/hip_runtime.h>

#define D 128
#define NG 256

typedef __attribute__((ext_vector_type(8))) short bf16x8;
typedef __attribute__((ext_vector_type(4))) float f32x4;
typedef __attribute__((ext_vector_type(4))) float f4;
typedef __attribute__((ext_vector_type(2))) int i2;
typedef __attribute__((ext_vector_type(4))) ushort u16x4;

__device__ inline ushort f2bf(float f) {
  uint b = __float_as_uint(f);
  return (ushort)((b + 0x7fffu + ((b >> 16) & 1u)) >> 16);
}
__device__ inline float bf2f(ushort u) { return __uint_as_float((uint)u << 16); }

// ------- fused: deg histogram + per-graph counts + x->bf16 + W->bf16^T -------
__global__ __launch_bounds__(256) void prep_kernel(
    const int* __restrict__ ei, int* __restrict__ deg,
    const int* __restrict__ batch, const int* __restrict__ primary,
    int* __restrict__ ncount, int* __restrict__ ccnt,
    const float* __restrict__ x, ushort* __restrict__ xb,
    const float* __restrict__ W1, const float* __restrict__ W2,
    ushort* __restrict__ W1T, ushort* __restrict__ W2T, int E, int N, int total4) {
  int i = blockIdx.x * blockDim.x + threadIdx.x;
  if (i < E) atomicAdd(&deg[ei[E + i]], 1);
  if (i < N) {
    int g = batch[i];
    atomicAdd(&ncount[g], 1);
    if (primary[i] == 0) atomicAdd(&ccnt[g], 1);
  }
  if (i < total4) {
    f4 v = __builtin_nontemporal_load(&((const f4*)x)[i]);
    u16x4 o;
    o.x = f2bf(v.x); o.y = f2bf(v.y); o.z = f2bf(v.z); o.w = f2bf(v.w);
    ((u16x4*)xb)[i] = o;
  }
  if (i < 2 * D * D) {
    int w = i >> 14;
    int k = (i >> 7) & 127;
    int n = i & 127;
    const float* src = w ? W2 : W1;
    ushort* dst = w ? W2T : W1T;
    dst[n * 128 + k] = f2bf(src[k * 128 + n]);
  }
}

// ---------------- scan over N (3-phase) ----------------
__global__ __launch_bounds__(256) void scan_block_sums(const int* __restrict__ deg,
                                                       int* __restrict__ bsum, int N) {
  __shared__ int red[256];
  int t = threadIdx.x;
  int base = blockIdx.x * 1024;
  int s = 0;
#pragma unroll
  for (int j = 0; j < 4; ++j) {
    int i = base + t * 4 + j;
    if (i < N) s += deg[i];
  }
  red[t] = s;
  __syncthreads();
  for (int o = 128; o > 0; o >>= 1) {
    if (t < o) red[t] += red[t + o];
    __syncthreads();
  }
  if (t == 0) bsum[blockIdx.x] = red[0];
}

// parallel exclusive scan of nb (<=128) block sums
__global__ void scan_bsum(int* __restrict__ bsum, int nb) {
  __shared__ int a[128];
  int t = threadIdx.x;
  int v = (t < nb) ? bsum[t] : 0;
  a[t] = v;
  __syncthreads();
  for (int o = 1; o < 128; o <<= 1) {
    int u = (t >= o) ? a[t - o] : 0;
    __syncthreads();
    a[t] += u;
    __syncthreads();
  }
  if (t < nb) bsum[t] = a[t] - v;
}

__global__ __launch_bounds__(256) void scan_final(const int* __restrict__ deg,
                                                  const int* __restrict__ bsum,
                                                  int* __restrict__ off, int N) {
  __shared__ int ts[256];
  int t = threadIdx.x;
  int base = blockIdx.x * 1024;
  int v[4];
  int s = 0;
#pragma unroll
  for (int j = 0; j < 4; ++j) {
    int i = base + t * 4 + j;
    v[j] = (i < N) ? deg[i] : 0;
    s += v[j];
  }
  ts[t] = s;
  __syncthreads();
  for (int o = 1; o < 256; o <<= 1) {
    int u = (t >= o) ? ts[t - o] : 0;
    __syncthreads();
    ts[t] += u;
    __syncthreads();
  }
  int excl = ts[t] - s + bsum[blockIdx.x];
#pragma unroll
  for (int j = 0; j < 4; ++j) {
    int i = base + t * 4 + j;
    if (i < N) off[i] = excl;
    excl += v[j];
    if (i == N - 1) off[N] = excl;
  }
}

// ---------------- CSR fill: csr[off[dst]+slot] = (src, e) ----------------
__global__ __launch_bounds__(256) void fill_kernel(const int* __restrict__ ei,
                                                   const int* __restrict__ off,
                                                   int* __restrict__ cursor,
                                                   i2* __restrict__ csr, int E) {
  int e = blockIdx.x * blockDim.x + threadIdx.x;
  if (e >= E) return;
  int s = ei[e];
  int d = ei[E + e];
  int slot = atomicAdd(&cursor[d], 1);
  i2 v;
  v.x = s;
  v.y = e;
  csr[off[d] + slot] = v;
}

// ---------------- exclusive scan of graph sizes -> gstart ----------------
__global__ void scan_kernel(const int* __restrict__ ncount, int* __restrict__ gstart) {
  __shared__ int a[NG];
  int tx = threadIdx.x;
  int v = ncount[tx];
  a[tx] = v;
  __syncthreads();
  for (int off = 1; off < NG; off <<= 1) {
    int u = (tx >= off) ? a[tx - off] : 0;
    __syncthreads();
    a[tx] += u;
    __syncthreads();
  }
  gstart[tx] = a[tx] - v;
  if (tx == NG - 1) gstart[NG] = a[tx];
}

// ---------------- per-graph stable ranks: primary -> p, cond -> ~p ----------------
__global__ __launch_bounds__(256) void rank_kernel(const int* __restrict__ primary,
                                                   const int* __restrict__ gstart,
                                                   const int* __restrict__ ccnt,
                                                   int* __restrict__ pos) {
  int g = blockIdx.x;
  int s = gstart[g], e = gstart[g + 1];
  int pcnt = (e - s) - ccnt[g];
  __shared__ int wcntP[4], wcntC[4];
  int prun = 0, crun = 0;
  for (int i0 = s; i0 < e; i0 += 256) {
    int n = i0 + threadIdx.x;
    bool valid = n < e;
    int isP = (valid && primary[n] == 1) ? 1 : 0;
    int isC = (valid && primary[n] != 1) ? 1 : 0;
    unsigned long long mP = __ballot(isP);
    unsigned long long mC = __ballot(isC);
    int lane = threadIdx.x & 63;
    int wid = threadIdx.x >> 6;
    if (lane == 0) { wcntP[wid] = __popcll(mP); wcntC[wid] = __popcll(mC); }
    __syncthreads();
    int preP = __popcll(mP & ((1ULL << lane) - 1ULL));
    int preC = __popcll(mC & ((1ULL << lane) - 1ULL));
    int woffP = 0, woffC = 0;
#pragma unroll
    for (int ww = 0; ww < 4; ++ww)
      if (ww < wid) { woffP += wcntP[ww]; woffC += wcntC[ww]; }
    int totP = wcntP[0] + wcntP[1] + wcntP[2] + wcntP[3];
    int totC = wcntC[0] + wcntC[1] + wcntC[2] + wcntC[3];
    if (valid) {
      if (isP)
        pos[n] = s + prun + woffP + preP;
      else
        pos[n] = ~(s + pcnt + crun + woffC + preC);
    }
    prun += totP;
    crun += totC;
    __syncthreads();
  }
}

// ---------------- FUSED gather + MFMA MLP (best-known configuration, R6) ----------------
// Block = 256 threads = 4 waves, owns 64 node rows.
// Phase A: 8 groups x 32 lanes gather y rows into swizzled LDS tile.
// Phase B: MFMA MLP (h = relu(y@W1+b1)@W2+b2) reading A-frags from LDS;
//          epilogue writes output rows via pos + cond-pool accumulation.
__global__ __launch_bounds__(256, 4) void fused_gather_mlp_kernel(
    const ushort* __restrict__ xb, const float* __restrict__ ea,
    const i2* __restrict__ csr, const int* __restrict__ off, float* __restrict__ out,
    const ushort* __restrict__ W1T, const float* __restrict__ b1,
    const ushort* __restrict__ W2T, const float* __restrict__ b2,
    const int* __restrict__ batch, const int* __restrict__ primary,
    const int* __restrict__ pos, float* __restrict__ csum, int N) {
  __shared__ ushort ylds[64][D];    // swizzled: byte ^= (row&7)<<4
  __shared__ ushort tl[4][16][D];   // per-wave relu(t) tile, XOR-swizzled cols
  __shared__ float csl[4][D];       // local csum for up to 4 graphs
  const int tid = threadIdx.x;
  const int base = blockIdx.x * 64;

  for (int i = tid; i < 4 * D; i += 256) ((float*)csl)[i] = 0.f;
  const int gmin = batch[base < N ? base : N - 1];

  // ---- Phase A: gather 8 rows per 32-lane group ----
  {
    const int gid = tid >> 5;
    const int c = tid & 31;
    const f4* ea4 = (const f4*)ea;
    const u16x4* xb4 = (const u16x4*)xb;
    for (int i = 0; i < 8; ++i) {
      const int m = gid * 8 + i;
      const int n = base + m;
      f4 acc = {0.f, 0.f, 0.f, 0.f};
      if (n < N) {
        u16x4 self = xb4[(size_t)n * 32 + c];
        acc.x = bf2f(self.x);
        acc.y = bf2f(self.y);
        acc.z = bf2f(self.z);
        acc.w = bf2f(self.w);
        int s = off[n], e = off[n + 1];
        int k = s;
        for (; k + 4 <= e; k += 4) {
          i2 p0 = csr[k];
          i2 p1 = csr[k + 1];
          i2 p2 = csr[k + 2];
          i2 p3 = csr[k + 3];
          f4 a0 = __builtin_nontemporal_load(&ea4[(size_t)p0.y * 32 + c]);
          f4 a1 = __builtin_nontemporal_load(&ea4[(size_t)p1.y * 32 + c]);
          f4 a2 = __builtin_nontemporal_load(&ea4[(size_t)p2.y * 32 + c]);
          f4 a3 = __builtin_nontemporal_load(&ea4[(size_t)p3.y * 32 + c]);
          u16x4 u0 = xb4[(size_t)p0.x * 32 + c];
          u16x4 u1 = xb4[(size_t)p1.x * 32 + c];
          u16x4 u2 = xb4[(size_t)p2.x * 32 + c];
          u16x4 u3 = xb4[(size_t)p3.x * 32 + c];
          acc.x += (a0.x + bf2f(u0.x)) + (a1.x + bf2f(u1.x));
          acc.y += (a0.y + bf2f(u0.y)) + (a1.y + bf2f(u1.y));
          acc.z += (a0.z + bf2f(u0.z)) + (a1.z + bf2f(u1.z));
          acc.w += (a0.w + bf2f(u0.w)) + (a1.w + bf2f(u1.w));
          acc.x += (a2.x + bf2f(u2.x)) + (a3.x + bf2f(u3.x));
          acc.y += (a2.y + bf2f(u2.y)) + (a3.y + bf2f(u3.y));
          acc.z += (a2.z + bf2f(u2.z)) + (a3.z + bf2f(u3.z));
          acc.w += (a2.w + bf2f(u2.w)) + (a3.w + bf2f(u3.w));
        }
        for (; k < e; ++k) {
          i2 p0 = csr[k];
          f4 a0 = __builtin_nontemporal_load(&ea4[(size_t)p0.y * 32 + c]);
          u16x4 u0 = xb4[(size_t)p0.x * 32 + c];
          acc.x += a0.x + bf2f(u0.x);
          acc.y += a0.y + bf2f(u0.y);
          acc.z += a0.z + bf2f(u0.z);
          acc.w += a0.w + bf2f(u0.w);
        }
      }
      u16x4 o;
      o.x = f2bf(acc.x);
      o.y = f2bf(acc.y);
      o.z = f2bf(acc.z);
      o.w = f2bf(acc.w);
      *(u16x4*)((char*)&ylds[m][0] + ((c * 8) ^ (i << 4))) = o;  // (m&7)==i
    }
  }
  __syncthreads();

  // ---- Phase B: MFMA MLP ----
  const int w = tid >> 6;
  const int l = tid & 63;
  const int lr = l & 15;
  const int lg = l >> 4;
  const int m0 = base + w * 16;

  // GEMM1: t = relu(y @ W1 + b1)
  f32x4 acc[8];
#pragma unroll
  for (int t = 0; t < 8; ++t) {
    float bv = b1[t * 16 + lr];
    acc[t][0] = bv; acc[t][1] = bv; acc[t][2] = bv; acc[t][3] = bv;
  }
  const char* arow_base = (const char*)&ylds[w * 16 + lr][0];
  const int arow_swz = (lr & 7) << 4;
#pragma unroll
  for (int kk = 0; kk < 4; ++kk) {
    bf16x8 a = *(const bf16x8*)(arow_base + ((kk * 64 + lg * 16) ^ arow_swz));
#pragma unroll
    for (int t = 0; t < 8; ++t) {
      bf16x8 b = *(const bf16x8*)&W1T[(size_t)(t * 16 + lr) * D + kk * 32 + lg * 8];
      acc[t] = __builtin_amdgcn_mfma_f32_16x16x32_bf16(a, b, acc[t], 0, 0, 0);
    }
  }
  // relu + cvt + store to per-wave LDS tile ([m][n], col ^= (m&7)<<3)
#pragma unroll
  for (int t = 0; t < 8; ++t) {
#pragma unroll
    for (int r = 0; r < 4; ++r) {
      float v = acc[t][r];
      v = v > 0.f ? v : 0.f;
      int m = lg * 4 + r;
      int col = (t * 16 + lr) ^ ((m & 7) << 3);
      tl[w][m][col] = f2bf(v);
    }
  }
  __syncthreads();

  // GEMM2: h = t @ W2 + b2
  f32x4 acc2[8];
#pragma unroll
  for (int t = 0; t < 8; ++t) {
    float bv = b2[t * 16 + lr];
    acc2[t][0] = bv; acc2[t][1] = bv; acc2[t][2] = bv; acc2[t][3] = bv;
  }
#pragma unroll
  for (int kk = 0; kk < 4; ++kk) {
    bf16x8 a = *(const bf16x8*)&tl[w][lr][(kk * 32 + lg * 8) ^ ((lr & 7) << 3)];
#pragma unroll
    for (int t = 0; t < 8; ++t) {
      bf16x8 b = *(const bf16x8*)&W2T[(size_t)(t * 16 + lr) * D + kk * 32 + lg * 8];
      acc2[t] = __builtin_amdgcn_mfma_f32_16x16x32_bf16(a, b, acc2[t], 0, 0, 0);
    }
  }

  // epilogue: direct out-row writes + cond-pool accumulation
#pragma unroll
  for (int r = 0; r < 4; ++r) {
    int m = m0 + lg * 4 + r;
    if (m >= N) continue;
    int p = pos[m];
    if (p >= 0) {  // primary: left half = h
      size_t ro = (size_t)p * 256;
#pragma unroll
      for (int t = 0; t < 8; ++t)
        __builtin_nontemporal_store(acc2[t][r], &out[ro + t * 16 + lr]);
    } else {  // cond: zero full row, accumulate into pool sum
      size_t ro = (size_t)(~p) * 256;
#pragma unroll
      for (int t = 0; t < 8; ++t) {
        __builtin_nontemporal_store(0.0f, &out[ro + t * 16 + lr]);
        __builtin_nontemporal_store(0.0f, &out[ro + 128 + t * 16 + lr]);
      }
      int g = batch[m];
      int gl = g - gmin;
      if (gl < 4) {
#pragma unroll
        for (int t = 0; t < 8; ++t) atomicAdd(&csl[gl][t * 16 + lr], acc2[t][r]);
      } else {
#pragma unroll
        for (int t = 0; t < 8; ++t)
          unsafeAtomicAdd(&csum[(size_t)g * D + t * 16 + lr], acc2[t][r]);
      }
    }
  }
  __syncthreads();
  for (int i = tid; i < 4 * D; i += 256) {
    float v = ((float*)csl)[i];
    if (v != 0.f) {
      int gl = i >> 7, c = i & 127;
      unsafeAtomicAdd(&csum[(size_t)(gmin + gl) * D + c], v);
    }
  }
}

// ---------------- right half of primary rows: out[p][128+c] = csum[g][c]/cnt ----------------
__global__ __launch_bounds__(256) void poolwrite_kernel(const float* __restrict__ csum,
                                                        const int* __restrict__ ccnt,
                                                        const int* __restrict__ batch,
                                                        const int* __restrict__ pos,
                                                        float* __restrict__ out, int N) {
  long long tid = (long long)blockIdx.x * blockDim.x + threadIdx.x;
  int n = (int)(tid >> 5);
  int c = (int)(tid & 31);
  if (n >= N) return;
  int p = pos[n];
  if (p < 0) return;
  int g = batch[n];
  int cnt = ccnt[g];
  f4 v = {0.f, 0.f, 0.f, 0.f};
  if (cnt > 0) {
    f4 s4 = ((const f4*)csum)[(size_t)g * 32 + c];
    float inv = 1.0f / (float)cnt;
    v = s4 * inv;
  }
  __builtin_nontemporal_store(v, &((f4*)out)[(size_t)p * 64 + 32 + c]);
}

extern "C" void kernel_launch(void* const* d_in, const int* in_sizes, int n_in,
                              void* d_out, int out_size, void* d_ws, size_t ws_size,
                              hipStream_t stream) {
  const float* x = (const float*)d_in[0];
  const int* ei = (const int*)d_in[1];
  const float* ea = (const float*)d_in[2];
  const int* batch = (const int*)d_in[3];
  const int* primary = (const int*)d_in[4];
  const float* W1 = (const float*)d_in[5];
  const float* b1 = (const float*)d_in[6];
  const float* W2 = (const float*)d_in[7];
  const float* b2 = (const float*)d_in[8];
  float* out = (float*)d_out;

  const int N = in_sizes[0] / D;  // 100000
  const int E = in_sizes[1] / 2;  // 1600000
  const int nb = (N + 1023) / 1024;
  const int total4 = N * D / 4;

  // workspace layout
  float* csum = (float*)d_ws;                        // NG*D
  ushort* xb = (ushort*)(csum + (size_t)NG * D);     // N*D bf16
  ushort* W1T = xb + (size_t)N * D;                  // 128*128 bf16
  ushort* W2T = W1T + D * D;                         // 128*128 bf16
  i2* csr = (i2*)(W2T + D * D);                      // E int2
  int* ip = (int*)(csr + (size_t)E);
  int* deg = ip;                                     // N
  int* off = deg + N;                                // N+1 (pad 4)
  int* cursor = off + N + 4;                         // N
  int* bsum = cursor + N;                            // nb (pad 128)
  int* ccnt = bsum + 128;                            // NG
  int* ncount = ccnt + NG;                           // NG
  int* gstart = ncount + NG;                         // NG+1 (pad 260)
  int* pos = gstart + 260;                           // N

  hipMemsetAsync(csum, 0, (size_t)NG * D * 4, stream);
  hipMemsetAsync(deg, 0, (size_t)N * 4, stream);
  hipMemsetAsync(cursor, 0, (size_t)N * 4, stream);
  hipMemsetAsync(ccnt, 0, (size_t)NG * 2 * 4, stream);  // ccnt + ncount contiguous

  prep_kernel<<<(total4 + 255) / 256, 256, 0, stream>>>(ei, deg, batch, primary, ncount, ccnt,
                                                        x, xb, W1, W2, W1T, W2T, E, N, total4);
  scan_block_sums<<<nb, 256, 0, stream>>>(deg, bsum, N);
  scan_bsum<<<1, 128, 0, stream>>>(bsum, nb);
  scan_final<<<nb, 256, 0, stream>>>(deg, bsum, off, N);
  fill_kernel<<<(E + 255) / 256, 256, 0, stream>>>(ei, off, cursor, csr, E);
  scan_kernel<<<1, NG, 0, stream>>>(ncount, gstart);
  rank_kernel<<<NG, 256, 0, stream>>>(primary, gstart, ccnt, pos);
  fused_gather_mlp_kernel<<<(N + 63) / 64, 256, 0, stream>>>(xb, ea, csr, off, out, W1T, b1,
                                                             W2T, b2, batch, primary, pos,
                                                             csum, N);
  poolwrite_kernel<<<(int)(((long long)N * 32 + 255) / 256), 256, 0, stream>>>(csum, ccnt, batch,
                                                                               pos, out, N);
}